// Round 9
// baseline (290.691 us; speedup 1.0000x reference)
//
#include <hip/hip_runtime.h>
#include <cmath>

// EntNet forward v4: fully fused scan, MT=32 rows/block for occupancy.
constexpr int T = 4, B = 64, L = 32, E = 1024, D = 256;
constexpr int MT = 32;            // entity rows per block
constexpr int NBLK = E / MT;      // 32

typedef __attribute__((ext_vector_type(8))) short short8;
typedef __attribute__((ext_vector_type(4))) float f32x4;
typedef __attribute__((ext_vector_type(4))) unsigned short u16x4;

static __device__ __forceinline__ unsigned short f2bf(float x) {
  unsigned int u = __builtin_bit_cast(unsigned int, x);
  unsigned int r = u + 0x7fffu + ((u >> 16) & 1u);   // RNE
  return (unsigned short)(r >> 16);
}
static __device__ __forceinline__ float bf2f(unsigned short s) {
  unsigned int u = ((unsigned int)s) << 16;
  return __builtin_bit_cast(float, u);
}

// ---------------------------------------------------------------------------
__global__ void k_h(const float* __restrict__ embed, const float* __restrict__ pos_w,
                    const int* __restrict__ sentences, const int* __restrict__ lengths,
                    float* __restrict__ h) {
  int tb = blockIdx.x;
  int d  = threadIdx.x;
  const int* sent = sentences + tb * L;
  int len = lengths[tb];
  float acc = 0.f;
  for (int l = 0; l < len; ++l) {
    int tok = sent[l];
    acc += embed[(size_t)tok * D + d] * pos_w[l * D + d];
  }
  h[(size_t)tb * D + d] = acc;
}

// ---------------------------------------------------------------------------
__global__ void k_oc(const float* __restrict__ h, const float* __restrict__ Wc,
                     float* __restrict__ oc) {
  int tb = blockIdx.x;
  int f  = threadIdx.x;
  __shared__ float hs[D];
  hs[f] = h[(size_t)tb * D + f];
  __syncthreads();
  float acc = 0.f;
  for (int d0 = 0; d0 < D; d0 += 4) {
    float4 hv = *(const float4*)&hs[d0];
    acc += hv.x * Wc[(d0 + 0) * D + f] + hv.y * Wc[(d0 + 1) * D + f]
         + hv.z * Wc[(d0 + 2) * D + f] + hv.w * Wc[(d0 + 3) * D + f];
  }
  oc[(size_t)tb * D + f] = acc;
}

// ---------------------------------------------------------------------------
// Fragment-layout weights: idx(n,k) = (((n>>4)*8 + (k>>5))*64 + ((k>>3)&3)*16
// + (n&15))*8 + (k&7). One coalesced b128 per (n-tile,kb) per wave.
__global__ void k_wt(const float* __restrict__ Wv, const float* __restrict__ Wk,
                     unsigned short* __restrict__ Wvfrag,
                     unsigned short* __restrict__ Wkfrag) {
  int n = blockIdx.x, k = threadIdx.x;
  int idx = (((n >> 4) * 8 + (k >> 5)) * 64 + ((k >> 3) & 3) * 16 + (n & 15)) * 8 + (k & 7);
  Wvfrag[idx] = f2bf(Wv[(size_t)k * D + n]);
  Wkfrag[idx] = f2bf(Wk[(size_t)k * D + n]);
}

// ---------------------------------------------------------------------------
// Fused scan, 32-row tile: stage keys -> ok=keys@Wk (regs) + ksc[4];
// stage entities; 4 on-chip steps {ents@Wv, gate, renorm, next-dist}.
__global__ __launch_bounds__(256, 4) void k_scan(
    const float* __restrict__ entities,
    const float* __restrict__ keys,
    const unsigned short* __restrict__ Wvfrag,
    const unsigned short* __restrict__ Wkfrag,
    const float* __restrict__ h,       // [T][B][D]
    const float* __restrict__ oc,      // [T][B][D]
    const float* __restrict__ prelu_w, // [D]
    float* __restrict__ out_ents,
    float* __restrict__ joint) {
  int b = blockIdx.y, e0 = blockIdx.x * MT;
  int tid = threadIdx.x;
  int lane = tid & 63, w = tid >> 6;
  int col16 = lane & 15, kg = lane >> 4;
  const int aswz = (col16 & 7) << 3;

  __shared__ unsigned short es[MT * D];   // 16 KB swizzled (keys, then ents)
  __shared__ float hs4[T][D];             // 4 KB
  __shared__ float ocs4[T][D];            // 4 KB
  __shared__ float pws[D];
  __shared__ float ksc_s[T][MT];
  __shared__ float dist_s[MT];
  __shared__ float red0[4][MT], red1[4][MT];
  __shared__ float inv_s[MT];

#pragma unroll
  for (int t = 0; t < T; ++t) {
    hs4[t][tid]  = h[((size_t)t * B + b) * D + tid];
    ocs4[t][tid] = oc[((size_t)t * B + b) * D + tid];
  }
  pws[tid] = prelu_w[tid];
  __syncthreads();

  // ---- phase 1: stage keys (f32->bf16 swizzled, chunk-wise) + ksc dots
  {
    int r = tid >> 3, c0 = (tid & 7) * 32;
    const float4* src = (const float4*)(keys + ((size_t)b * E + e0 + r) * D + c0);
    float p[T] = {0.f, 0.f, 0.f, 0.f};
#pragma unroll
    for (int ch = 0; ch < 4; ++ch) {
      float4 v0 = src[ch * 2], v1 = src[ch * 2 + 1];
      int c = c0 + ch * 8;
#pragma unroll
      for (int t = 0; t < T; ++t) {
        p[t] += v0.x * hs4[t][c]     + v0.y * hs4[t][c + 1]
              + v0.z * hs4[t][c + 2] + v0.w * hs4[t][c + 3]
              + v1.x * hs4[t][c + 4] + v1.y * hs4[t][c + 5]
              + v1.z * hs4[t][c + 6] + v1.w * hs4[t][c + 7];
      }
      unsigned short u[8];
      u[0] = f2bf(v0.x); u[1] = f2bf(v0.y); u[2] = f2bf(v0.z); u[3] = f2bf(v0.w);
      u[4] = f2bf(v1.x); u[5] = f2bf(v1.y); u[6] = f2bf(v1.z); u[7] = f2bf(v1.w);
      int idx = (r * D + c) ^ ((r & 7) << 3);
      *(short8*)&es[idx] = *(const short8*)&u[0];
    }
#pragma unroll
    for (int t = 0; t < T; ++t) {
      p[t] += __shfl_xor(p[t], 1);
      p[t] += __shfl_xor(p[t], 2);
      p[t] += __shfl_xor(p[t], 4);
    }
    if ((tid & 7) == 0) {
#pragma unroll
      for (int t = 0; t < T; ++t) ksc_s[t][r] = p[t];
    }
  }
  __syncthreads();

  // ---- phase 2: ok = keys @ Wk -> bf16 regs
  u16x4 ok4[2][4];
  {
    f32x4 acc[2][4];
#pragma unroll
    for (int rt = 0; rt < 2; ++rt)
#pragma unroll
      for (int ct = 0; ct < 4; ++ct) acc[rt][ct] = (f32x4)(0.f);
#pragma unroll 2
    for (int kb = 0; kb < 8; ++kb) {
      int k0 = kb * 32 + kg * 8;
      short8 a[2];
#pragma unroll
      for (int rt = 0; rt < 2; ++rt)
        a[rt] = *(const short8*)&es[((rt * 16 + col16) * D + k0) ^ aswz];
      short8 bv[4];
#pragma unroll
      for (int ct = 0; ct < 4; ++ct)
        bv[ct] = *(const short8*)&Wkfrag[(size_t)(((w * 4 + ct) * 8 + kb) * 64 + lane) * 8];
#pragma unroll
      for (int rt = 0; rt < 2; ++rt)
#pragma unroll
        for (int ct = 0; ct < 4; ++ct)
          acc[rt][ct] = __builtin_amdgcn_mfma_f32_16x16x32_bf16(a[rt], bv[ct], acc[rt][ct], 0, 0, 0);
    }
#pragma unroll
    for (int rt = 0; rt < 2; ++rt)
#pragma unroll
      for (int ct = 0; ct < 4; ++ct)
#pragma unroll
        for (int r = 0; r < 4; ++r) ok4[rt][ct][r] = f2bf(acc[rt][ct][r]);
  }
  __syncthreads();   // es (keys) reads complete

  // ---- phase 3: stage entities f32 -> es + dist_0
  {
    int r = tid >> 3, c0 = (tid & 7) * 32;
    const float4* src = (const float4*)(entities + ((size_t)b * E + e0 + r) * D + c0);
    float p = 0.f;
#pragma unroll
    for (int ch = 0; ch < 4; ++ch) {
      float4 v0 = src[ch * 2], v1 = src[ch * 2 + 1];
      int c = c0 + ch * 8;
      p += v0.x * hs4[0][c]     + v0.y * hs4[0][c + 1]
         + v0.z * hs4[0][c + 2] + v0.w * hs4[0][c + 3]
         + v1.x * hs4[0][c + 4] + v1.y * hs4[0][c + 5]
         + v1.z * hs4[0][c + 6] + v1.w * hs4[0][c + 7];
      unsigned short u[8];
      u[0] = f2bf(v0.x); u[1] = f2bf(v0.y); u[2] = f2bf(v0.z); u[3] = f2bf(v0.w);
      u[4] = f2bf(v1.x); u[5] = f2bf(v1.y); u[6] = f2bf(v1.z); u[7] = f2bf(v1.w);
      int idx = (r * D + c) ^ ((r & 7) << 3);
      *(short8*)&es[idx] = *(const short8*)&u[0];
    }
    p += __shfl_xor(p, 1);
    p += __shfl_xor(p, 2);
    p += __shfl_xor(p, 4);
    if ((tid & 7) == 0)
      dist_s[r] = 1.f / (1.f + expf(-(p + ksc_s[0][r])));
  }
  __syncthreads();

  // ---- phase 4: the 4-step scan, fully on-chip
  size_t obase = ((size_t)b * E + e0) * D;
#pragma unroll
  for (int t = 0; t < T; ++t) {
    f32x4 acc[2][4];
#pragma unroll
    for (int rt = 0; rt < 2; ++rt)
#pragma unroll
      for (int ct = 0; ct < 4; ++ct) acc[rt][ct] = (f32x4)(0.f);
#pragma unroll 2
    for (int kb = 0; kb < 8; ++kb) {
      int k0 = kb * 32 + kg * 8;
      short8 a[2];
#pragma unroll
      for (int rt = 0; rt < 2; ++rt)
        a[rt] = *(const short8*)&es[((rt * 16 + col16) * D + k0) ^ aswz];
      short8 bv[4];
#pragma unroll
      for (int ct = 0; ct < 4; ++ct)
        bv[ct] = *(const short8*)&Wvfrag[(size_t)(((w * 4 + ct) * 8 + kb) * 64 + lane) * 8];
#pragma unroll
      for (int rt = 0; rt < 2; ++rt)
#pragma unroll
        for (int ct = 0; ct < 4; ++ct)
          acc[rt][ct] = __builtin_amdgcn_mfma_f32_16x16x32_bf16(a[rt], bv[ct], acc[rt][ct], 0, 0, 0);
    }

    // epilogue: pre = acc + oc + ok; gated PReLU blend with old ents
#pragma unroll
    for (int rt = 0; rt < 2; ++rt)
#pragma unroll
      for (int ct = 0; ct < 4; ++ct) {
        int n = w * 64 + ct * 16 + col16;
        float ocv = ocs4[t][n], pwv = pws[n];
#pragma unroll
        for (int r = 0; r < 4; ++r) {
          int m = rt * 16 + kg * 4 + r;
          float pre = acc[rt][ct][r] + ocv + bf2f(ok4[rt][ct][r]);
          float pr = pre >= 0.f ? pre : pwv * pre;
          float de = dist_s[m];
          float ev = bf2f(es[(m * D + n) ^ ((m & 7) << 3)]);
          acc[rt][ct][r] = de * pr + (1.f - de) * ev;
        }
      }

    // per-row sumsq + next-h dot (fused 16-lane reductions)
#pragma unroll
    for (int rt = 0; rt < 2; ++rt)
#pragma unroll
      for (int r = 0; r < 4; ++r) {
        float s = acc[rt][0][r] * acc[rt][0][r] + acc[rt][1][r] * acc[rt][1][r]
                + acc[rt][2][r] * acc[rt][2][r] + acc[rt][3][r] * acc[rt][3][r];
        float dn = 0.f;
        if (t < 3) {
#pragma unroll
          for (int ct = 0; ct < 4; ++ct) {
            int n = w * 64 + ct * 16 + col16;
            dn += acc[rt][ct][r] * hs4[t + 1 < T ? t + 1 : 0][n];
          }
        }
        s += __shfl_xor(s, 1); s += __shfl_xor(s, 2);
        s += __shfl_xor(s, 4); s += __shfl_xor(s, 8);
        if (t < 3) {
          dn += __shfl_xor(dn, 1); dn += __shfl_xor(dn, 2);
          dn += __shfl_xor(dn, 4); dn += __shfl_xor(dn, 8);
        }
        if (col16 == 0) {
          int m = rt * 16 + kg * 4 + r;
          red0[w][m] = s;
          red1[w][m] = dn;
        }
      }
    __syncthreads();
    if (tid < MT) {
      float ss = red0[0][tid] + red0[1][tid] + red0[2][tid] + red0[3][tid];
      float iv = rsqrtf(ss);
      inv_s[tid] = iv;
      if (t < 3) {
        float dd = red1[0][tid] + red1[1][tid] + red1[2][tid] + red1[3][tid];
        dist_s[tid] = 1.f / (1.f + expf(-(iv * dd + ksc_s[t + 1 < T ? t + 1 : 0][tid])));
      }
    }
    __syncthreads();

    // scale + store back (es for next step; global + joint on last)
    if (t < 3) {
#pragma unroll
      for (int rt = 0; rt < 2; ++rt)
#pragma unroll
        for (int ct = 0; ct < 4; ++ct) {
          int n = w * 64 + ct * 16 + col16;
#pragma unroll
          for (int r = 0; r < 4; ++r) {
            int m = rt * 16 + kg * 4 + r;
            es[(m * D + n) ^ ((m & 7) << 3)] = f2bf(acc[rt][ct][r] * inv_s[m]);
          }
        }
    } else {
      float jacc[4] = {0.f, 0.f, 0.f, 0.f};
#pragma unroll
      for (int rt = 0; rt < 2; ++rt)
#pragma unroll
        for (int ct = 0; ct < 4; ++ct) {
          int n = w * 64 + ct * 16 + col16;
#pragma unroll
          for (int r = 0; r < 4; ++r) {
            int m = rt * 16 + kg * 4 + r;
            float val = acc[rt][ct][r] * inv_s[m];
            out_ents[obase + (size_t)m * D + n] = val;
            jacc[ct] += dist_s[m] * val;
          }
        }
#pragma unroll
      for (int ct = 0; ct < 4; ++ct) {
        float s = jacc[ct];
        s += __shfl_xor(s, 16);
        s += __shfl_xor(s, 32);
        if (kg == 0) atomicAdd(&joint[(size_t)b * D + w * 64 + ct * 16 + col16], s);
      }
    }
    __syncthreads();
  }
}

// ---------------------------------------------------------------------------
extern "C" void kernel_launch(void* const* d_in, const int* in_sizes, int n_in,
                              void* d_out, int out_size, void* d_ws, size_t ws_size,
                              hipStream_t stream) {
  const float* embed    = (const float*)d_in[0];
  const float* pos_w    = (const float*)d_in[1];
  const float* keys     = (const float*)d_in[2];
  const float* entities = (const float*)d_in[3];
  const float* Wk       = (const float*)d_in[4];
  const float* Wv       = (const float*)d_in[5];
  const float* Wc       = (const float*)d_in[6];
  const float* prelu_w  = (const float*)d_in[7];
  const int* sentences  = (const int*)d_in[8];
  const int* lengths    = (const int*)d_in[9];

  float* out_ents  = (float*)d_out;
  float* out_joint = out_ents + (size_t)B * E * D;

  float* h  = (float*)d_ws;                                // T*B*D
  float* oc = h + (size_t)T * B * D;                       // T*B*D
  unsigned short* Wvfrag = (unsigned short*)(oc + (size_t)T * B * D);  // D*D
  unsigned short* Wkfrag = Wvfrag + (size_t)D * D;         // D*D

  hipMemsetAsync(out_joint, 0, (size_t)B * D * sizeof(float), stream);

  k_h<<<T * B, D, 0, stream>>>(embed, pos_w, sentences, lengths, h);
  k_oc<<<T * B, D, 0, stream>>>(h, Wc, oc);
  k_wt<<<D, D, 0, stream>>>(Wv, Wk, Wvfrag, Wkfrag);

  dim3 grid(NBLK, B);
  k_scan<<<grid, 256, 0, stream>>>(entities, keys, Wvfrag, Wkfrag,
                                   h, oc, prelu_w, out_ents, out_joint);

  (void)in_sizes; (void)n_in; (void)out_size; (void)ws_size;
}

// Round 10
// 140.514 us; speedup vs baseline: 2.0688x; 2.0688x over previous
//
#include <hip/hip_runtime.h>
#include <cmath>

// EntNet forward v5: fused scan, MT=32, launch_bounds(256,3), ok in LDS.
constexpr int T = 4, B = 64, L = 32, E = 1024, D = 256;
constexpr int MT = 32;            // entity rows per block
constexpr int NBLK = E / MT;      // 32

typedef __attribute__((ext_vector_type(8))) short short8;
typedef __attribute__((ext_vector_type(4))) float f32x4;
typedef __attribute__((ext_vector_type(4))) unsigned short u16x4;

static __device__ __forceinline__ unsigned short f2bf(float x) {
  unsigned int u = __builtin_bit_cast(unsigned int, x);
  unsigned int r = u + 0x7fffu + ((u >> 16) & 1u);   // RNE
  return (unsigned short)(r >> 16);
}
static __device__ __forceinline__ float bf2f(unsigned short s) {
  unsigned int u = ((unsigned int)s) << 16;
  return __builtin_bit_cast(float, u);
}

// ---------------------------------------------------------------------------
__global__ void k_h(const float* __restrict__ embed, const float* __restrict__ pos_w,
                    const int* __restrict__ sentences, const int* __restrict__ lengths,
                    float* __restrict__ h) {
  int tb = blockIdx.x;
  int d  = threadIdx.x;
  const int* sent = sentences + tb * L;
  int len = lengths[tb];
  float acc = 0.f;
  for (int l = 0; l < len; ++l) {
    int tok = sent[l];
    acc += embed[(size_t)tok * D + d] * pos_w[l * D + d];
  }
  h[(size_t)tb * D + d] = acc;
}

// ---------------------------------------------------------------------------
__global__ void k_oc(const float* __restrict__ h, const float* __restrict__ Wc,
                     float* __restrict__ oc) {
  int tb = blockIdx.x;
  int f  = threadIdx.x;
  __shared__ float hs[D];
  hs[f] = h[(size_t)tb * D + f];
  __syncthreads();
  float acc = 0.f;
  for (int d0 = 0; d0 < D; d0 += 4) {
    float4 hv = *(const float4*)&hs[d0];
    acc += hv.x * Wc[(d0 + 0) * D + f] + hv.y * Wc[(d0 + 1) * D + f]
         + hv.z * Wc[(d0 + 2) * D + f] + hv.w * Wc[(d0 + 3) * D + f];
  }
  oc[(size_t)tb * D + f] = acc;
}

// ---------------------------------------------------------------------------
// Fragment-layout weights: idx(n,k) = (((n>>4)*8 + (k>>5))*64 + ((k>>3)&3)*16
// + (n&15))*8 + (k&7). One coalesced b128 per (n-tile,kb) per wave.
__global__ void k_wt(const float* __restrict__ Wv, const float* __restrict__ Wk,
                     unsigned short* __restrict__ Wvfrag,
                     unsigned short* __restrict__ Wkfrag) {
  int n = blockIdx.x, k = threadIdx.x;
  int idx = (((n >> 4) * 8 + (k >> 5)) * 64 + ((k >> 3) & 3) * 16 + (n & 15)) * 8 + (k & 7);
  Wvfrag[idx] = f2bf(Wv[(size_t)k * D + n]);
  Wkfrag[idx] = f2bf(Wk[(size_t)k * D + n]);
}

// ---------------------------------------------------------------------------
// Fused scan, 32-row tile: stage keys -> ok=keys@Wk (LDS) + ksc[4];
// stage entities; 4 on-chip steps {ents@Wv, gate, renorm, next-dist}.
__global__ __launch_bounds__(256, 3) void k_scan(
    const float* __restrict__ entities,
    const float* __restrict__ keys,
    const unsigned short* __restrict__ Wvfrag,
    const unsigned short* __restrict__ Wkfrag,
    const float* __restrict__ h,       // [T][B][D]
    const float* __restrict__ oc,      // [T][B][D]
    const float* __restrict__ prelu_w, // [D]
    float* __restrict__ out_ents,
    float* __restrict__ joint) {
  int b = blockIdx.y, e0 = blockIdx.x * MT;
  int tid = threadIdx.x;
  int lane = tid & 63, w = tid >> 6;
  int col16 = lane & 15, kg = lane >> 4;
  const int aswz = (col16 & 7) << 3;

  __shared__ unsigned short es[MT * D];    // 16 KB swizzled (keys, then ents)
  __shared__ unsigned short oks[MT * D];   // 16 KB, C-fragment order
  __shared__ float hs4[T][D];              // 4 KB
  __shared__ float ocs4[T][D];             // 4 KB
  __shared__ float pws[D];
  __shared__ float ksc_s[T][MT];
  __shared__ float dist_s[MT];
  __shared__ float red0[4][MT], red1[4][MT];
  __shared__ float inv_s[MT];

#pragma unroll
  for (int t = 0; t < T; ++t) {
    hs4[t][tid]  = h[((size_t)t * B + b) * D + tid];
    ocs4[t][tid] = oc[((size_t)t * B + b) * D + tid];
  }
  pws[tid] = prelu_w[tid];
  __syncthreads();

  // ---- phase 1: stage keys (f32->bf16 swizzled, chunk-wise) + ksc dots
  {
    int r = tid >> 3, c0 = (tid & 7) * 32;
    const float4* src = (const float4*)(keys + ((size_t)b * E + e0 + r) * D + c0);
    float p[T] = {0.f, 0.f, 0.f, 0.f};
#pragma unroll
    for (int ch = 0; ch < 4; ++ch) {
      float4 v0 = src[ch * 2], v1 = src[ch * 2 + 1];
      int c = c0 + ch * 8;
#pragma unroll
      for (int t = 0; t < T; ++t) {
        p[t] += v0.x * hs4[t][c]     + v0.y * hs4[t][c + 1]
              + v0.z * hs4[t][c + 2] + v0.w * hs4[t][c + 3]
              + v1.x * hs4[t][c + 4] + v1.y * hs4[t][c + 5]
              + v1.z * hs4[t][c + 6] + v1.w * hs4[t][c + 7];
      }
      unsigned short u[8];
      u[0] = f2bf(v0.x); u[1] = f2bf(v0.y); u[2] = f2bf(v0.z); u[3] = f2bf(v0.w);
      u[4] = f2bf(v1.x); u[5] = f2bf(v1.y); u[6] = f2bf(v1.z); u[7] = f2bf(v1.w);
      int idx = (r * D + c) ^ ((r & 7) << 3);
      *(short8*)&es[idx] = *(const short8*)&u[0];
    }
#pragma unroll
    for (int t = 0; t < T; ++t) {
      p[t] += __shfl_xor(p[t], 1);
      p[t] += __shfl_xor(p[t], 2);
      p[t] += __shfl_xor(p[t], 4);
    }
    if ((tid & 7) == 0) {
#pragma unroll
      for (int t = 0; t < T; ++t) ksc_s[t][r] = p[t];
    }
  }
  __syncthreads();

  // ---- phase 2: ok = keys @ Wk -> bf16 LDS (C-fragment order)
  {
    f32x4 acc[2][4];
#pragma unroll
    for (int rt = 0; rt < 2; ++rt)
#pragma unroll
      for (int ct = 0; ct < 4; ++ct) acc[rt][ct] = (f32x4)(0.f);
#pragma unroll 2
    for (int kb = 0; kb < 8; ++kb) {
      int k0 = kb * 32 + kg * 8;
      short8 a[2];
#pragma unroll
      for (int rt = 0; rt < 2; ++rt)
        a[rt] = *(const short8*)&es[((rt * 16 + col16) * D + k0) ^ aswz];
      short8 bv[4];
#pragma unroll
      for (int ct = 0; ct < 4; ++ct)
        bv[ct] = *(const short8*)&Wkfrag[(size_t)(((w * 4 + ct) * 8 + kb) * 64 + lane) * 8];
#pragma unroll
      for (int rt = 0; rt < 2; ++rt)
#pragma unroll
        for (int ct = 0; ct < 4; ++ct)
          acc[rt][ct] = __builtin_amdgcn_mfma_f32_16x16x32_bf16(a[rt], bv[ct], acc[rt][ct], 0, 0, 0);
    }
#pragma unroll
    for (int rt = 0; rt < 2; ++rt)
#pragma unroll
      for (int ct = 0; ct < 4; ++ct) {
        u16x4 o;
#pragma unroll
        for (int r = 0; r < 4; ++r) o[r] = f2bf(acc[rt][ct][r]);
        *(u16x4*)&oks[(((w * 2 + rt) * 4 + ct) * 64 + lane) * 4] = o;
      }
  }
  __syncthreads();   // es (keys) reads complete; oks visible

  // ---- phase 3: stage entities f32 -> es + dist_0
  {
    int r = tid >> 3, c0 = (tid & 7) * 32;
    const float4* src = (const float4*)(entities + ((size_t)b * E + e0 + r) * D + c0);
    float p = 0.f;
#pragma unroll
    for (int ch = 0; ch < 4; ++ch) {
      float4 v0 = src[ch * 2], v1 = src[ch * 2 + 1];
      int c = c0 + ch * 8;
      p += v0.x * hs4[0][c]     + v0.y * hs4[0][c + 1]
         + v0.z * hs4[0][c + 2] + v0.w * hs4[0][c + 3]
         + v1.x * hs4[0][c + 4] + v1.y * hs4[0][c + 5]
         + v1.z * hs4[0][c + 6] + v1.w * hs4[0][c + 7];
      unsigned short u[8];
      u[0] = f2bf(v0.x); u[1] = f2bf(v0.y); u[2] = f2bf(v0.z); u[3] = f2bf(v0.w);
      u[4] = f2bf(v1.x); u[5] = f2bf(v1.y); u[6] = f2bf(v1.z); u[7] = f2bf(v1.w);
      int idx = (r * D + c) ^ ((r & 7) << 3);
      *(short8*)&es[idx] = *(const short8*)&u[0];
    }
    p += __shfl_xor(p, 1);
    p += __shfl_xor(p, 2);
    p += __shfl_xor(p, 4);
    if ((tid & 7) == 0)
      dist_s[r] = 1.f / (1.f + expf(-(p + ksc_s[0][r])));
  }
  __syncthreads();

  // ---- phase 4: the 4-step scan, fully on-chip
  size_t obase = ((size_t)b * E + e0) * D;
#pragma unroll
  for (int t = 0; t < T; ++t) {
    f32x4 acc[2][4];
#pragma unroll
    for (int rt = 0; rt < 2; ++rt)
#pragma unroll
      for (int ct = 0; ct < 4; ++ct) acc[rt][ct] = (f32x4)(0.f);
#pragma unroll 2
    for (int kb = 0; kb < 8; ++kb) {
      int k0 = kb * 32 + kg * 8;
      short8 a[2];
#pragma unroll
      for (int rt = 0; rt < 2; ++rt)
        a[rt] = *(const short8*)&es[((rt * 16 + col16) * D + k0) ^ aswz];
      short8 bv[4];
#pragma unroll
      for (int ct = 0; ct < 4; ++ct)
        bv[ct] = *(const short8*)&Wvfrag[(size_t)(((w * 4 + ct) * 8 + kb) * 64 + lane) * 8];
#pragma unroll
      for (int rt = 0; rt < 2; ++rt)
#pragma unroll
        for (int ct = 0; ct < 4; ++ct)
          acc[rt][ct] = __builtin_amdgcn_mfma_f32_16x16x32_bf16(a[rt], bv[ct], acc[rt][ct], 0, 0, 0);
    }

    // epilogue: pre = acc + oc + ok; gated PReLU blend with old ents
#pragma unroll
    for (int rt = 0; rt < 2; ++rt)
#pragma unroll
      for (int ct = 0; ct < 4; ++ct) {
        int n = w * 64 + ct * 16 + col16;
        float ocv = ocs4[t][n], pwv = pws[n];
        u16x4 ok4 = *(const u16x4*)&oks[(((w * 2 + rt) * 4 + ct) * 64 + lane) * 4];
#pragma unroll
        for (int r = 0; r < 4; ++r) {
          int m = rt * 16 + kg * 4 + r;
          float pre = acc[rt][ct][r] + ocv + bf2f(ok4[r]);
          float pr = pre >= 0.f ? pre : pwv * pre;
          float de = dist_s[m];
          float ev = bf2f(es[(m * D + n) ^ ((m & 7) << 3)]);
          acc[rt][ct][r] = de * pr + (1.f - de) * ev;
        }
      }

    // per-row sumsq + next-h dot (fused 16-lane reductions)
#pragma unroll
    for (int rt = 0; rt < 2; ++rt)
#pragma unroll
      for (int r = 0; r < 4; ++r) {
        float s = acc[rt][0][r] * acc[rt][0][r] + acc[rt][1][r] * acc[rt][1][r]
                + acc[rt][2][r] * acc[rt][2][r] + acc[rt][3][r] * acc[rt][3][r];
        float dn = 0.f;
        if (t < 3) {
#pragma unroll
          for (int ct = 0; ct < 4; ++ct) {
            int n = w * 64 + ct * 16 + col16;
            dn += acc[rt][ct][r] * hs4[t + 1 < T ? t + 1 : 0][n];
          }
        }
        s += __shfl_xor(s, 1); s += __shfl_xor(s, 2);
        s += __shfl_xor(s, 4); s += __shfl_xor(s, 8);
        if (t < 3) {
          dn += __shfl_xor(dn, 1); dn += __shfl_xor(dn, 2);
          dn += __shfl_xor(dn, 4); dn += __shfl_xor(dn, 8);
        }
        if (col16 == 0) {
          int m = rt * 16 + kg * 4 + r;
          red0[w][m] = s;
          red1[w][m] = dn;
        }
      }
    __syncthreads();
    if (tid < MT) {
      float ss = red0[0][tid] + red0[1][tid] + red0[2][tid] + red0[3][tid];
      float iv = rsqrtf(ss);
      inv_s[tid] = iv;
      if (t < 3) {
        float dd = red1[0][tid] + red1[1][tid] + red1[2][tid] + red1[3][tid];
        dist_s[tid] = 1.f / (1.f + expf(-(iv * dd + ksc_s[t + 1 < T ? t + 1 : 0][tid])));
      }
    }
    __syncthreads();

    // scale + store back (es for next step; global + joint on last)
    if (t < 3) {
#pragma unroll
      for (int rt = 0; rt < 2; ++rt)
#pragma unroll
        for (int ct = 0; ct < 4; ++ct) {
          int n = w * 64 + ct * 16 + col16;
#pragma unroll
          for (int r = 0; r < 4; ++r) {
            int m = rt * 16 + kg * 4 + r;
            es[(m * D + n) ^ ((m & 7) << 3)] = f2bf(acc[rt][ct][r] * inv_s[m]);
          }
        }
    } else {
      float jacc[4] = {0.f, 0.f, 0.f, 0.f};
#pragma unroll
      for (int rt = 0; rt < 2; ++rt)
#pragma unroll
        for (int ct = 0; ct < 4; ++ct) {
          int n = w * 64 + ct * 16 + col16;
#pragma unroll
          for (int r = 0; r < 4; ++r) {
            int m = rt * 16 + kg * 4 + r;
            float val = acc[rt][ct][r] * inv_s[m];
            out_ents[obase + (size_t)m * D + n] = val;
            jacc[ct] += dist_s[m] * val;
          }
        }
#pragma unroll
      for (int ct = 0; ct < 4; ++ct) {
        float s = jacc[ct];
        s += __shfl_xor(s, 16);
        s += __shfl_xor(s, 32);
        if (kg == 0) atomicAdd(&joint[(size_t)b * D + w * 64 + ct * 16 + col16], s);
      }
    }
    __syncthreads();
  }
}

// ---------------------------------------------------------------------------
extern "C" void kernel_launch(void* const* d_in, const int* in_sizes, int n_in,
                              void* d_out, int out_size, void* d_ws, size_t ws_size,
                              hipStream_t stream) {
  const float* embed    = (const float*)d_in[0];
  const float* pos_w    = (const float*)d_in[1];
  const float* keys     = (const float*)d_in[2];
  const float* entities = (const float*)d_in[3];
  const float* Wk       = (const float*)d_in[4];
  const float* Wv       = (const float*)d_in[5];
  const float* Wc       = (const float*)d_in[6];
  const float* prelu_w  = (const float*)d_in[7];
  const int* sentences  = (const int*)d_in[8];
  const int* lengths    = (const int*)d_in[9];

  float* out_ents  = (float*)d_out;
  float* out_joint = out_ents + (size_t)B * E * D;

  float* h  = (float*)d_ws;                                // T*B*D
  float* oc = h + (size_t)T * B * D;                       // T*B*D
  unsigned short* Wvfrag = (unsigned short*)(oc + (size_t)T * B * D);  // D*D
  unsigned short* Wkfrag = Wvfrag + (size_t)D * D;         // D*D

  hipMemsetAsync(out_joint, 0, (size_t)B * D * sizeof(float), stream);

  k_h<<<T * B, D, 0, stream>>>(embed, pos_w, sentences, lengths, h);
  k_oc<<<T * B, D, 0, stream>>>(h, Wc, oc);
  k_wt<<<D, D, 0, stream>>>(Wv, Wk, Wvfrag, Wkfrag);

  dim3 grid(NBLK, B);
  k_scan<<<grid, 256, 0, stream>>>(entities, keys, Wvfrag, Wkfrag,
                                   h, oc, prelu_w, out_ents, out_joint);

  (void)in_sizes; (void)n_in; (void)out_size; (void)ws_size;
}